// Round 8
// baseline (187.037 us; speedup 1.0000x reference)
//
#include <hip/hip_runtime.h>

#define NH 8
#define DH 64
#define SL 1024
#define NB 8
#define DIN 512
#define DOUT 512
#define PS 72  // P-tile LDS row stride in ushorts

typedef __bf16 bf16x8 __attribute__((ext_vector_type(8)));
typedef float floatx4 __attribute__((ext_vector_type(4)));
typedef unsigned short ushortx8 __attribute__((ext_vector_type(8)));

__device__ __forceinline__ unsigned short f2bf(float f) {
    unsigned int u = __builtin_bit_cast(unsigned int, f);
    u += 0x7FFFu + ((u >> 16) & 1u);
    return (unsigned short)(u >> 16);
}

__device__ __forceinline__ floatx4 mfma_bf16(bf16x8 a, bf16x8 b, floatx4 c) {
    return __builtin_amdgcn_mfma_f32_16x16x32_bf16(a, b, c, 0, 0, 0);
}

// bf16-truncate-pack two floats into one u32 (low short = bf(a), high = bf(b))
__device__ __forceinline__ unsigned int pack_bf2(float a, float b) {
    return __builtin_amdgcn_perm(__builtin_bit_cast(unsigned int, b),
                                 __builtin_bit_cast(unsigned int, a), 0x07060302u);
}

// X fp32 -> bf16 fragment-blocked: xb[z][(row/16)*64 + k/8][row%16][k%8].
// Each thread emits 4 rows x 8 k = one full 64-B line (no partial-line HBM traffic).
__global__ __launch_bounds__(256) void xbf_kernel(const float* __restrict__ Qs,
                                                  const float* __restrict__ Ks,
                                                  const float* __restrict__ Vs,
                                                  unsigned short* __restrict__ xb) {
    const int z = blockIdx.y;
    const float* X = (z == 0) ? Qs : (z == 1 ? Ks : Vs);
    const int u = blockIdx.x * 256 + threadIdx.x;
    const int c = u & 63;        // k-chunk
    const int row0 = (u >> 6) * 4;
    ushortx8 ob[4];
#pragma unroll
    for (int j = 0; j < 4; ++j) {
        const float4 a = *(const float4*)(X + (row0 + j) * DIN + c * 8);
        const float4 b = *(const float4*)(X + (row0 + j) * DIN + c * 8 + 4);
        ob[j][0] = f2bf(a.x); ob[j][1] = f2bf(a.y); ob[j][2] = f2bf(a.z); ob[j][3] = f2bf(a.w);
        ob[j][4] = f2bf(b.x); ob[j][5] = f2bf(b.y); ob[j][6] = f2bf(b.z); ob[j][7] = f2bf(b.w);
    }
    unsigned short* dst = xb + z * 8192 * DIN + ((row0 >> 4) * 64 + c) * 128 + (row0 & 15) * 8;
#pragma unroll
    for (int j = 0; j < 4; ++j) *(ushortx8*)(dst + j * 8) = ob[j];
}

// W -> transposed bf16 fragment-blocked: wt[z][(n/16)*64 + k/8][n%16][k%8]
__global__ __launch_bounds__(256) void wt_kernel(const float* __restrict__ WQ,
                                                 const float* __restrict__ WK,
                                                 const float* __restrict__ WV,
                                                 unsigned short* __restrict__ wt) {
    __shared__ unsigned short tile[64][72];  // 16B-aligned rows
    const int z = blockIdx.z;
    const float* W = (z == 0) ? WQ : (z == 1 ? WK : WV);
    const int k0 = blockIdx.y * 64, n0 = blockIdx.x * 64;
    const int tn = threadIdx.x & 63, tk = threadIdx.x >> 6;
#pragma unroll
    for (int i = 0; i < 16; ++i) {
        const int kk = tk + i * 4;
        tile[tn][kk] = f2bf(W[(k0 + kk) * DOUT + n0 + tn]);  // coalesced over n
    }
    __syncthreads();
    unsigned short* o = wt + z * DIN * DOUT;
#pragma unroll
    for (int it = 0; it < 2; ++it) {
        const int ch = it * 256 + threadIdx.x;   // 512 chunks: 64 n x 8 kc
        const int n_loc = ch >> 3, kc = ch & 7;
        const ushortx8 v = *(const ushortx8*)&tile[n_loc][kc * 8];
        const int n = n0 + n_loc, k = k0 + kc * 8;
        *(ushortx8*)(o + ((n >> 4) * 64 + (k >> 3)) * 128 + (n & 15) * 8) = v;
    }
}

// GEMM with NO LDS staging: A/B fragments loaded directly from blocked global
// layouts (each frag = one coalesced 1 KB wave load, L2-hot). Epilogue builds
// the 32 KB output image in LDS, copied out 16B-coalesced.
__global__ __launch_bounds__(256) void proj_kernel(const unsigned short* __restrict__ xbt,
                                                   const unsigned short* __restrict__ wtt,
                                                   unsigned short* __restrict__ qw,
                                                   unsigned short* __restrict__ ks,
                                                   unsigned short* __restrict__ vs) {
    __shared__ __align__(16) unsigned short S[16384];  // epilogue image only
    const int z = blockIdx.z;
    const int mblk = blockIdx.x, nblk = blockIdx.y;
    const int w = threadIdx.x >> 6, lane = threadIdx.x & 63;
    const int l15 = lane & 15, quad = lane >> 4;
    const int wm = w >> 1, wn = w & 1;
    const int loff = quad * 128 + l15 * 8;  // in-frag lane offset (contiguous 1 KB/wave)
    const unsigned short* Ab = xbt + z * (8192 * DIN) + (mblk * 8 + wm * 4) * 8192 + loff;
    const unsigned short* Bb = wtt + z * (DIN * DOUT) + (nblk * 8 + wn * 4) * 8192 + loff;

    floatx4 acc[4][4];
#pragma unroll
    for (int i = 0; i < 4; ++i)
#pragma unroll
        for (int j = 0; j < 4; ++j) acc[i][j] = floatx4{0.f, 0.f, 0.f, 0.f};

    for (int kblk = 0; kblk < 8; ++kblk) {
        bf16x8 af[2][4], bfr[2][4];
#pragma unroll
        for (int ksub = 0; ksub < 2; ++ksub) {
            const int ko = (kblk * 8 + ksub * 4) * 128;
#pragma unroll
            for (int mi = 0; mi < 4; ++mi) af[ksub][mi] = *(const bf16x8*)(Ab + mi * 8192 + ko);
#pragma unroll
            for (int nt = 0; nt < 4; ++nt) bfr[ksub][nt] = *(const bf16x8*)(Bb + nt * 8192 + ko);
        }
#pragma unroll
        for (int ksub = 0; ksub < 2; ++ksub)
#pragma unroll
            for (int mi = 0; mi < 4; ++mi)
#pragma unroll
                for (int nt = 0; nt < 4; ++nt)
                    acc[mi][nt] = mfma_bf16(af[ksub][mi], bfr[ksub][nt], acc[mi][nt]);
    }

    // ---- epilogue: build output-byte-exact image in LDS ----
#pragma unroll
    for (int mi = 0; mi < 4; ++mi)
#pragma unroll
        for (int nt = 0; nt < 4; ++nt)
#pragma unroll
            for (int r = 0; r < 4; ++r) {
                const int a = wm * 64 + mi * 16 + quad * 4 + r;   // tile row 0..127
                const int c = wn * 64 + nt * 16 + l15;            // tile col 0..127
                const int h = c >> 6, dh = c & 63;
                float v = acc[mi][nt][r];
                int lidx;
                if (z == 0) {
                    v *= 0.18033688f;  // 0.125 * log2(e): attn uses exp2
                    // q fragment-blocked: [h][ltile 8][kc 8][l15][8]
                    lidx = h * 8192 + (a >> 4) * 1024 + (dh >> 3) * 128 + (a & 15) * 8 + (dh & 7);
                } else if (z == 1) {
                    lidx = (((((h << 3) + (a >> 4)) << 1) | (dh >> 5))) * 512 +
                           (a & 15) * 32 + (dh & 31);
                } else {
                    const int s64 = ((a & 15) << 2) | ((a >> 4) & 3);
                    lidx = ((((h << 1) | (a >> 6)) << 1) | (s64 >> 5)) * 2048 +
                           dh * 32 + (s64 & 31);
                }
                S[lidx] = f2bf(v);
            }
    __syncthreads();

    const int b = mblk >> 3;
    const int li0 = (mblk & 7) * 128;
    const int tid = threadIdx.x;
    unsigned short* outp = (z == 0) ? qw : (z == 1 ? ks : vs);
#pragma unroll
    for (int j = 0; j < 8; ++j) {
        const int off = j * 2048 + tid * 8;
        const ushortx8 val = *(const ushortx8*)(S + off);
        int gidx;
        if (z == 0) {
            const int h = off >> 13, o13 = off & 8191;
            gidx = ((b * 8 + nblk * 2 + h) * 64 + (li0 >> 4) + (o13 >> 10)) * 1024 + (o13 & 1023);
        } else if (z == 1) {
            const int region = off >> 9, pos = off & 511;
            const int h = region >> 4, g = (region >> 1) & 7, d5 = region & 1;
            gidx = (((b * 8 + nblk * 2 + h) * 64 + (li0 >> 4) + g) * 2 + d5) * 512 + pos;
        } else {
            const int region = off >> 11, pos = off & 2047;
            const int h = region >> 2, l6 = (region >> 1) & 1, s5 = region & 1;
            gidx = ((b * 8 + nblk * 2 + h) * 32 + (li0 >> 5) + l6 * 2 + s5) * 2048 + pos;
        }
        *(ushortx8*)(outp + gidx) = val;
    }
}

// Causal flash attention, split-K (unchanged from R7 except fragment-blocked Q load).
__global__ __launch_bounds__(256) void attn_kernel(const unsigned short* __restrict__ qw,
                                                   const unsigned short* __restrict__ ksp,
                                                   const unsigned short* __restrict__ vsp,
                                                   float* __restrict__ out) {
    __shared__ union {
        unsigned short Ps[4][16 * PS];
        float Cb[2][64][21];
    } sh;
    const int w = threadIdx.x >> 6;
    const int lane = threadIdx.x & 63;
    const int l15 = lane & 15, quad = lane >> 4;
    const int bh = blockIdx.y;
    const int b = bh >> 3, h = bh & 7;
    const int tile = (w < 2) ? blockIdx.x : 63 - blockIdx.x;
    const int half = w & 1;
    const int m0 = tile * 16;

    const unsigned short* qp = qw + (bh * 64 + tile) * 1024 + quad * 128 + l15 * 8;
    const bf16x8 aQ0 = *(const bf16x8*)qp;
    const bf16x8 aQ1 = *(const bf16x8*)(qp + 512);

    const unsigned short* ksb = ksp + (bh * 64) * 2 * 512 + l15 * 32 + quad * 8;
    const unsigned short* vsb = vsp + (bh * 32 * 64 + l15) * 32 + quad * 8;
    unsigned short* myPs = sh.Ps[w];

    float lrow[4] = {0.f, 0.f, 0.f, 0.f};
    floatx4 o0 = {0.f, 0.f, 0.f, 0.f}, o1 = o0, o2 = o0, o3 = o0;
    const floatx4 zf = {0.f, 0.f, 0.f, 0.f};

    auto TAIL = [&](int kt, floatx4* s, bool domask, const bf16x8* v0, const bf16x8* v1) {
#pragma unroll
        for (int r = 0; r < 4; ++r) {
            const int row = m0 + quad * 4 + r;
            float p[4];
#pragma unroll
            for (int t = 0; t < 4; ++t) {
                float e = __builtin_amdgcn_exp2f(s[t][r]);
                if (domask && (kt + t * 16 + l15 > row)) e = 0.f;
                p[t] = e;
            }
            lrow[r] += (p[0] + p[1]) + (p[2] + p[3]);
            uint2 pk;
            pk.x = pack_bf2(p[0], p[1]);
            pk.y = pack_bf2(p[2], p[3]);
            *(uint2*)(myPs + (quad * 4 + r) * PS + l15 * 4) = pk;
        }
        __builtin_amdgcn_wave_barrier();
        const bf16x8 aP0 = *(const bf16x8*)(myPs + l15 * PS + quad * 8);
        const bf16x8 aP1 = *(const bf16x8*)(myPs + l15 * PS + 32 + quad * 8);
        __builtin_amdgcn_wave_barrier();
        o0 = mfma_bf16(aP1, v1[0], mfma_bf16(aP0, v0[0], o0));
        o1 = mfma_bf16(aP1, v1[1], mfma_bf16(aP0, v0[1], o1));
        o2 = mfma_bf16(aP1, v1[2], mfma_bf16(aP0, v0[2], o2));
        o3 = mfma_bf16(aP1, v1[3], mfma_bf16(aP0, v0[3], o3));
    };

    auto BODY = [&](int kt) {
        const unsigned short* vb = vsb + (kt >> 5) * 2048;
        bf16x8 v0[4], v1[4];
#pragma unroll
        for (int dt = 0; dt < 4; ++dt) {
            v0[dt] = *(const bf16x8*)(vb + dt * 512);
            v1[dt] = *(const bf16x8*)(vb + dt * 512 + 2048);
        }
        const unsigned short* kp = ksb + (kt >> 4) * 1024;
        floatx4 s[4];
#pragma unroll
        for (int t = 0; t < 4; ++t) {
            const bf16x8 k0 = *(const bf16x8*)(kp + t * 1024);
            const bf16x8 k1 = *(const bf16x8*)(kp + t * 1024 + 512);
            s[t] = mfma_bf16(aQ1, k1, mfma_bf16(aQ0, k0, zf));
        }
        TAIL(kt, s, false, v0, v1);
    };

    auto BODYM = [&](int kt) {
        const unsigned short* vb = vsb + (kt >> 5) * 2048;
        bf16x8 v0[4], v1[4];
#pragma unroll
        for (int dt = 0; dt < 4; ++dt) {
            v0[dt] = *(const bf16x8*)(vb + dt * 512);
            v1[dt] = *(const bf16x8*)(vb + dt * 512 + 2048);
        }
        const unsigned short* kp = ksb + (kt >> 4) * 1024;
        floatx4 s[4] = {zf, zf, zf, zf};
#pragma unroll
        for (int t = 0; t < 4; ++t) {
            if (kt + t * 16 <= m0 + 15) {
                const bf16x8 k0 = *(const bf16x8*)(kp + t * 1024);
                const bf16x8 k1 = *(const bf16x8*)(kp + t * 1024 + 512);
                s[t] = mfma_bf16(aQ1, k1, mfma_bf16(aQ0, k0, zf));
            }
        }
        TAIL(kt, s, true, v0, v1);
    };

    const int nf = (tile + 4) >> 2;
    const int last = nf - 1;
    for (int j = half; j < last; j += 2) BODY(j * 64);
    if ((last & 1) == half) BODYM(last * 64);

    // combine split-K partners via LDS (pure addition; union with Ps -> barrier first)
    __syncthreads();
    if (half == 1) {
        float* cb = &sh.Cb[w >> 1][lane][0];
#pragma unroll
        for (int r = 0; r < 4; ++r) {
            cb[r] = o0[r]; cb[4 + r] = o1[r];
            cb[8 + r] = o2[r]; cb[12 + r] = o3[r];
            cb[16 + r] = lrow[r];
        }
    }
    __syncthreads();
    if (half == 0) {
        const float* cb = &sh.Cb[w >> 1][lane][0];
#pragma unroll
        for (int r = 0; r < 4; ++r) {
            o0[r] += cb[r]; o1[r] += cb[4 + r];
            o2[r] += cb[8 + r]; o3[r] += cb[12 + r];
            lrow[r] += cb[16 + r];
        }
#pragma unroll
        for (int r = 0; r < 4; ++r) {
            float l = lrow[r];
            l += __shfl_xor(l, 1);
            l += __shfl_xor(l, 2);
            l += __shfl_xor(l, 4);
            l += __shfl_xor(l, 8);
            const float inv = 1.0f / l;
            const int row = m0 + quad * 4 + r;
            float* op = out + (b * SL + row) * DOUT + h * DH + l15;
            op[0]  = o0[r] * inv;
            op[16] = o1[r] * inv;
            op[32] = o2[r] * inv;
            op[48] = o3[r] * inv;
        }
    }
}

extern "C" void kernel_launch(void* const* d_in, const int* in_sizes, int n_in,
                              void* d_out, int out_size, void* d_ws, size_t ws_size,
                              hipStream_t stream) {
    const float* Qs = (const float*)d_in[0];
    const float* Ks = (const float*)d_in[1];
    const float* Vs = (const float*)d_in[2];
    const float* WQ = (const float*)d_in[3];
    const float* WK = (const float*)d_in[4];
    const float* WV = (const float*)d_in[5];
    float* out = (float*)d_out;

    unsigned short* xb = (unsigned short*)d_ws;          // 3*8192*512 (frag-blocked)
    unsigned short* wt = xb + 3 * 8192 * DIN;            // 3*512*512 (frag-blocked)
    unsigned short* qw = wt + 3 * DIN * DOUT;            // frag-blocked, pre-scaled
    unsigned short* ks = qw + NB * NH * SL * DH;         // blocked (as R7)
    unsigned short* vs = ks + NB * NH * SL * DH;         // blocked+permuted (as R7)

    xbf_kernel<<<dim3(512, 3), 256, 0, stream>>>(Qs, Ks, Vs, xb);
    wt_kernel<<<dim3(DOUT / 64, DIN / 64, 3), 256, 0, stream>>>(WQ, WK, WV, wt);
    proj_kernel<<<dim3(64, 4, 3), 256, 0, stream>>>(xb, wt, qw, ks, vs);
    attn_kernel<<<dim3(32, NB * NH), 256, 0, stream>>>(qw, ks, vs, out);
}

// Round 9
// 165.264 us; speedup vs baseline: 1.1317x; 1.1317x over previous
//
#include <hip/hip_runtime.h>

#define NH 8
#define DH 64
#define SL 1024
#define NB 8
#define DIN 512
#define DOUT 512
#define PS 72  // P-tile LDS row stride in ushorts

typedef __bf16 bf16x8 __attribute__((ext_vector_type(8)));
typedef float floatx4 __attribute__((ext_vector_type(4)));
typedef unsigned short ushortx8 __attribute__((ext_vector_type(8)));

__device__ __forceinline__ unsigned short f2bf(float f) {
    unsigned int u = __builtin_bit_cast(unsigned int, f);
    u += 0x7FFFu + ((u >> 16) & 1u);
    return (unsigned short)(u >> 16);
}

__device__ __forceinline__ floatx4 mfma_bf16(bf16x8 a, bf16x8 b, floatx4 c) {
    return __builtin_amdgcn_mfma_f32_16x16x32_bf16(a, b, c, 0, 0, 0);
}

__device__ __forceinline__ void gld_lds16(const unsigned short* g, unsigned short* l) {
    __builtin_amdgcn_global_load_lds(
        (const __attribute__((address_space(1))) unsigned int*)g,
        (__attribute__((address_space(3))) unsigned int*)l, 16, 0, 0);
}

// bf16-truncate-pack two floats into one u32 (low short = bf(a), high = bf(b))
__device__ __forceinline__ unsigned int pack_bf2(float a, float b) {
    return __builtin_amdgcn_perm(__builtin_bit_cast(unsigned int, b),
                                 __builtin_bit_cast(unsigned int, a), 0x07060302u);
}

// X fp32 -> bf16 in tiled+swizzled layout:
// xb[z][(row/128)*8 + k/64][row%128][ ((k%64/8) ^ (row&7))*8 + k%8 ]
__global__ __launch_bounds__(256) void xbf_kernel(const float* __restrict__ Qs,
                                                  const float* __restrict__ Ks,
                                                  const float* __restrict__ Vs,
                                                  unsigned short* __restrict__ xb) {
    const int z = blockIdx.y;
    const float* X = (z == 0) ? Qs : (z == 1 ? Ks : Vs);
    const int t = blockIdx.x * 256 + threadIdx.x;
    const int row = t >> 6, c = t & 63;
    const float4 a = *(const float4*)(X + t * 8);
    const float4 b = *(const float4*)(X + t * 8 + 4);
    ushortx8 o;
    o[0] = f2bf(a.x); o[1] = f2bf(a.y); o[2] = f2bf(a.z); o[3] = f2bf(a.w);
    o[4] = f2bf(b.x); o[5] = f2bf(b.y); o[6] = f2bf(b.z); o[7] = f2bf(b.w);
    const int dst = (((row >> 7) * 8 + (c >> 3)) * 128 + (row & 127)) * 64 +
                    (((c & 7) ^ (row & 7)) * 8);
    *(ushortx8*)(xb + z * 8192 * DIN + dst) = o;
}

// W -> transposed bf16, tiled+swizzled: wt[(z*4+n/128)*8 + k/64][n%128][swz chunk]
__global__ __launch_bounds__(256) void wt_kernel(const float* __restrict__ WQ,
                                                 const float* __restrict__ WK,
                                                 const float* __restrict__ WV,
                                                 unsigned short* __restrict__ wt) {
    __shared__ unsigned short tile[64][68];
    const int z = blockIdx.z;
    const float* W = (z == 0) ? WQ : (z == 1 ? WK : WV);
    const int k0 = blockIdx.y * 64, n0 = blockIdx.x * 64;
    const int tn = threadIdx.x & 63, tk = threadIdx.x >> 6;
#pragma unroll
    for (int i = 0; i < 16; ++i) {
        const int kk = tk + i * 4;
        tile[tn][kk] = f2bf(W[(k0 + kk) * DOUT + n0 + tn]);
    }
    __syncthreads();
#pragma unroll
    for (int i = 0; i < 16; ++i) {
        const int nn = tk + i * 4;
        const int n = n0 + nn, k = k0 + tn;
        const int dst = (((z * 4 + (n >> 7)) * 8 + (k >> 6)) * 128 + (n & 127)) * 64 +
                        ((((k >> 3) & 7) ^ (n & 7)) * 8) + (k & 7);
        wt[dst] = tile[nn][tn];
    }
}

// m97-style GEMM, 128x128xBK64, global_load_lds staging (R7 main loop — best
// measured), LDS-assembled epilogue. qw written fragment-blocked (R8's win).
__global__ __launch_bounds__(256) void proj_kernel(const unsigned short* __restrict__ xbt,
                                                   const unsigned short* __restrict__ wtt,
                                                   unsigned short* __restrict__ qw,
                                                   unsigned short* __restrict__ ks,
                                                   unsigned short* __restrict__ vs) {
    __shared__ __align__(16) unsigned short S[16384];  // As | Bs, reused as epilogue image
    unsigned short* As = S;
    unsigned short* Bs = S + 8192;
    const int z = blockIdx.z;
    const int mblk = blockIdx.x, nblk = blockIdx.y;
    const int w = threadIdx.x >> 6, lane = threadIdx.x & 63;
    const int l15 = lane & 15, quad = lane >> 4;
    const int wm = w >> 1, wn = w & 1;
    const int soff = lane * 8;  // identity: swizzle lives in the stored layout
    const unsigned short* Ab = xbt + z * (8192 * DIN) + mblk * 8 * 8192 + (w * 4) * 512 + soff;
    const unsigned short* Bb = wtt + (z * 4 + nblk) * 8 * 8192 + (w * 4) * 512 + soff;
    unsigned short* Asw = &As[(w * 4) * 512];
    unsigned short* Bsw = &Bs[(w * 4) * 512];

    floatx4 acc[4][4];
#pragma unroll
    for (int i = 0; i < 4; ++i)
#pragma unroll
        for (int j = 0; j < 4; ++j) acc[i][j] = floatx4{0.f, 0.f, 0.f, 0.f};

    for (int kblk = 0; kblk < 8; ++kblk) {
        __syncthreads();
#pragma unroll
        for (int i = 0; i < 4; ++i) {
            gld_lds16(Ab + kblk * 8192 + i * 512, Asw + i * 512);
            gld_lds16(Bb + kblk * 8192 + i * 512, Bsw + i * 512);
        }
        __syncthreads();
#pragma unroll
        for (int ksub = 0; ksub < 2; ++ksub) {
            bf16x8 af[4], bfr[4];
#pragma unroll
            for (int mi = 0; mi < 4; ++mi) {
                const int row = wm * 64 + mi * 16 + l15;
                af[mi] = *(const bf16x8*)&As[row * 64 + (((quad + ksub * 4) ^ (l15 & 7)) * 8)];
            }
#pragma unroll
            for (int nt = 0; nt < 4; ++nt) {
                const int row = wn * 64 + nt * 16 + l15;
                bfr[nt] = *(const bf16x8*)&Bs[row * 64 + (((quad + ksub * 4) ^ (l15 & 7)) * 8)];
            }
#pragma unroll
            for (int mi = 0; mi < 4; ++mi)
#pragma unroll
                for (int nt = 0; nt < 4; ++nt)
                    acc[mi][nt] = mfma_bf16(af[mi], bfr[nt], acc[mi][nt]);
        }
    }

    // ---- epilogue: build output-byte-exact image in LDS ----
    __syncthreads();
#pragma unroll
    for (int mi = 0; mi < 4; ++mi)
#pragma unroll
        for (int nt = 0; nt < 4; ++nt)
#pragma unroll
            for (int r = 0; r < 4; ++r) {
                const int a = wm * 64 + mi * 16 + quad * 4 + r;   // tile row 0..127
                const int c = wn * 64 + nt * 16 + l15;            // tile col 0..127
                const int h = c >> 6, dh = c & 63;
                float v = acc[mi][nt][r];
                int lidx;
                if (z == 0) {
                    v *= 0.18033688f;  // 0.125 * log2(e): attn uses exp2
                    // q fragment-blocked image: [h][ltile 8][kc 8][l15 16][8]
                    lidx = h * 8192 + (a >> 4) * 1024 + (dh >> 3) * 128 + (a & 15) * 8 + (dh & 7);
                } else if (z == 1) {
                    lidx = (((((h << 3) + (a >> 4)) << 1) | (dh >> 5))) * 512 +
                           (a & 15) * 32 + (dh & 31);
                } else {
                    const int s64 = ((a & 15) << 2) | ((a >> 4) & 3);
                    lidx = ((((h << 1) | (a >> 6)) << 1) | (s64 >> 5)) * 2048 +
                           dh * 32 + (s64 & 31);
                }
                S[lidx] = f2bf(v);
            }
    __syncthreads();

    const int b = mblk >> 3;
    const int li0 = (mblk & 7) * 128;
    const int tid = threadIdx.x;
    unsigned short* outp = (z == 0) ? qw : (z == 1 ? ks : vs);
#pragma unroll
    for (int j = 0; j < 8; ++j) {
        const int off = j * 2048 + tid * 8;
        const ushortx8 val = *(const ushortx8*)(S + off);
        int gidx;
        if (z == 0) {
            const int h = off >> 13, o13 = off & 8191;
            gidx = ((b * 8 + nblk * 2 + h) * 64 + (li0 >> 4) + (o13 >> 10)) * 1024 + (o13 & 1023);
        } else if (z == 1) {
            const int region = off >> 9, pos = off & 511;
            const int h = region >> 4, g = (region >> 1) & 7, d5 = region & 1;
            gidx = (((b * 8 + nblk * 2 + h) * 64 + (li0 >> 4) + g) * 2 + d5) * 512 + pos;
        } else {
            const int region = off >> 11, pos = off & 2047;
            const int h = region >> 2, l6 = (region >> 1) & 1, s5 = region & 1;
            gidx = ((b * 8 + nblk * 2 + h) * 32 + (li0 >> 5) + l6 * 2 + s5) * 2048 + pos;
        }
        *(ushortx8*)(outp + gidx) = val;
    }
}

// Causal flash attention, split-K (R8 version: fragment-blocked Q load).
__global__ __launch_bounds__(256) void attn_kernel(const unsigned short* __restrict__ qw,
                                                   const unsigned short* __restrict__ ksp,
                                                   const unsigned short* __restrict__ vsp,
                                                   float* __restrict__ out) {
    __shared__ union {
        unsigned short Ps[4][16 * PS];
        float Cb[2][64][21];
    } sh;
    const int w = threadIdx.x >> 6;
    const int lane = threadIdx.x & 63;
    const int l15 = lane & 15, quad = lane >> 4;
    const int bh = blockIdx.y;
    const int b = bh >> 3, h = bh & 7;
    const int tile = (w < 2) ? blockIdx.x : 63 - blockIdx.x;
    const int half = w & 1;
    const int m0 = tile * 16;

    const unsigned short* qp = qw + (bh * 64 + tile) * 1024 + quad * 128 + l15 * 8;
    const bf16x8 aQ0 = *(const bf16x8*)qp;
    const bf16x8 aQ1 = *(const bf16x8*)(qp + 512);

    const unsigned short* ksb = ksp + (bh * 64) * 2 * 512 + l15 * 32 + quad * 8;
    const unsigned short* vsb = vsp + (bh * 32 * 64 + l15) * 32 + quad * 8;
    unsigned short* myPs = sh.Ps[w];

    float lrow[4] = {0.f, 0.f, 0.f, 0.f};
    floatx4 o0 = {0.f, 0.f, 0.f, 0.f}, o1 = o0, o2 = o0, o3 = o0;
    const floatx4 zf = {0.f, 0.f, 0.f, 0.f};

    auto TAIL = [&](int kt, floatx4* s, bool domask, const bf16x8* v0, const bf16x8* v1) {
#pragma unroll
        for (int r = 0; r < 4; ++r) {
            const int row = m0 + quad * 4 + r;
            float p[4];
#pragma unroll
            for (int t = 0; t < 4; ++t) {
                float e = __builtin_amdgcn_exp2f(s[t][r]);
                if (domask && (kt + t * 16 + l15 > row)) e = 0.f;
                p[t] = e;
            }
            lrow[r] += (p[0] + p[1]) + (p[2] + p[3]);
            uint2 pk;
            pk.x = pack_bf2(p[0], p[1]);
            pk.y = pack_bf2(p[2], p[3]);
            *(uint2*)(myPs + (quad * 4 + r) * PS + l15 * 4) = pk;
        }
        __builtin_amdgcn_wave_barrier();
        const bf16x8 aP0 = *(const bf16x8*)(myPs + l15 * PS + quad * 8);
        const bf16x8 aP1 = *(const bf16x8*)(myPs + l15 * PS + 32 + quad * 8);
        __builtin_amdgcn_wave_barrier();
        o0 = mfma_bf16(aP1, v1[0], mfma_bf16(aP0, v0[0], o0));
        o1 = mfma_bf16(aP1, v1[1], mfma_bf16(aP0, v0[1], o1));
        o2 = mfma_bf16(aP1, v1[2], mfma_bf16(aP0, v0[2], o2));
        o3 = mfma_bf16(aP1, v1[3], mfma_bf16(aP0, v0[3], o3));
    };

    auto BODY = [&](int kt) {
        const unsigned short* vb = vsb + (kt >> 5) * 2048;
        bf16x8 v0[4], v1[4];
#pragma unroll
        for (int dt = 0; dt < 4; ++dt) {
            v0[dt] = *(const bf16x8*)(vb + dt * 512);
            v1[dt] = *(const bf16x8*)(vb + dt * 512 + 2048);
        }
        const unsigned short* kp = ksb + (kt >> 4) * 1024;
        floatx4 s[4];
#pragma unroll
        for (int t = 0; t < 4; ++t) {
            const bf16x8 k0 = *(const bf16x8*)(kp + t * 1024);
            const bf16x8 k1 = *(const bf16x8*)(kp + t * 1024 + 512);
            s[t] = mfma_bf16(aQ1, k1, mfma_bf16(aQ0, k0, zf));
        }
        TAIL(kt, s, false, v0, v1);
    };

    auto BODYM = [&](int kt) {
        const unsigned short* vb = vsb + (kt >> 5) * 2048;
        bf16x8 v0[4], v1[4];
#pragma unroll
        for (int dt = 0; dt < 4; ++dt) {
            v0[dt] = *(const bf16x8*)(vb + dt * 512);
            v1[dt] = *(const bf16x8*)(vb + dt * 512 + 2048);
        }
        const unsigned short* kp = ksb + (kt >> 4) * 1024;
        floatx4 s[4] = {zf, zf, zf, zf};
#pragma unroll
        for (int t = 0; t < 4; ++t) {
            if (kt + t * 16 <= m0 + 15) {
                const bf16x8 k0 = *(const bf16x8*)(kp + t * 1024);
                const bf16x8 k1 = *(const bf16x8*)(kp + t * 1024 + 512);
                s[t] = mfma_bf16(aQ1, k1, mfma_bf16(aQ0, k0, zf));
            }
        }
        TAIL(kt, s, true, v0, v1);
    };

    const int nf = (tile + 4) >> 2;
    const int last = nf - 1;
    for (int j = half; j < last; j += 2) BODY(j * 64);
    if ((last & 1) == half) BODYM(last * 64);

    // combine split-K partners via LDS (pure addition; union with Ps -> barrier first)
    __syncthreads();
    if (half == 1) {
        float* cb = &sh.Cb[w >> 1][lane][0];
#pragma unroll
        for (int r = 0; r < 4; ++r) {
            cb[r] = o0[r]; cb[4 + r] = o1[r];
            cb[8 + r] = o2[r]; cb[12 + r] = o3[r];
            cb[16 + r] = lrow[r];
        }
    }
    __syncthreads();
    if (half == 0) {
        const float* cb = &sh.Cb[w >> 1][lane][0];
#pragma unroll
        for (int r = 0; r < 4; ++r) {
            o0[r] += cb[r]; o1[r] += cb[4 + r];
            o2[r] += cb[8 + r]; o3[r] += cb[12 + r];
            lrow[r] += cb[16 + r];
        }
#pragma unroll
        for (int r = 0; r < 4; ++r) {
            float l = lrow[r];
            l += __shfl_xor(l, 1);
            l += __shfl_xor(l, 2);
            l += __shfl_xor(l, 4);
            l += __shfl_xor(l, 8);
            const float inv = 1.0f / l;
            const int row = m0 + quad * 4 + r;
            float* op = out + (b * SL + row) * DOUT + h * DH + l15;
            op[0]  = o0[r] * inv;
            op[16] = o1[r] * inv;
            op[32] = o2[r] * inv;
            op[48] = o3[r] * inv;
        }
    }
}

extern "C" void kernel_launch(void* const* d_in, const int* in_sizes, int n_in,
                              void* d_out, int out_size, void* d_ws, size_t ws_size,
                              hipStream_t stream) {
    const float* Qs = (const float*)d_in[0];
    const float* Ks = (const float*)d_in[1];
    const float* Vs = (const float*)d_in[2];
    const float* WQ = (const float*)d_in[3];
    const float* WK = (const float*)d_in[4];
    const float* WV = (const float*)d_in[5];
    float* out = (float*)d_out;

    unsigned short* xb = (unsigned short*)d_ws;          // 3*8192*512 (tiled+swz)
    unsigned short* wt = xb + 3 * 8192 * DIN;            // 3*512*512 (tiled+swz)
    unsigned short* qw = wt + 3 * DIN * DOUT;            // frag-blocked, pre-scaled
    unsigned short* ks = qw + NB * NH * SL * DH;         // blocked
    unsigned short* vs = ks + NB * NH * SL * DH;         // blocked+permuted

    xbf_kernel<<<dim3(8192 * DIN / (256 * 8), 3), 256, 0, stream>>>(Qs, Ks, Vs, xb);
    wt_kernel<<<dim3(DOUT / 64, DIN / 64, 3), 256, 0, stream>>>(WQ, WK, WV, wt);
    proj_kernel<<<dim3(64, 4, 3), 256, 0, stream>>>(xb, wt, qw, ks, vs);
    attn_kernel<<<dim3(32, NB * NH), 256, 0, stream>>>(qw, ks, vs, out);
}